// Round 4
// baseline (1227.367 us; speedup 1.0000x reference)
//
// HNHN layer on MI355X (gfx950). Round 4: transposed MMs, both pure bt-GEMMs.
//   K1:  rowsum -> node_card; B1 -> bf16 b1h[n][e] AND b1hT[e][n] (LDS tile transpose)
//   K2:  y0 = x0@W0; epilogue y0sT[c][n] = bf16(node_card[n]*y0[n,c]);  K2b aux rows
//   MM1T: out1pT[sp][c][e] = y0sT-slice @ b1hT   (M=272, N=8192, K=16384, splitK=8)
//         both operands k-contiguous -> async_copy16 direct, src-side XOR chunk swizzle
//   K3:  reduce 8 partials, x1 = p/d1sum + b01, LDS transpose -> out1[e][c], x1bf,
//        edge_card = colsum^-1.5 (aux rows 256/257)
//   K5:  y1sT[c][e] = bf16(edge_card[e]*(x1@W1));  K5b aux row
//   MM2T: out0pT[sp][c][n] = y1sT-slice @ b1h     (M=272, N=16384, K=8192, splitK=4)
//   K6:  reduce 4 partials, out0[n][c] = relu(s/d0sum + b10) via LDS transpose
#include <hip/hip_runtime.h>
#include <stdint.h>

#define NN 16384
#define NE 8192
#define CH 256
#define MM1_SPLIT 8
#define MM2_SPLIT 4

typedef __attribute__((ext_vector_type(8))) short bf16x8;
typedef __attribute__((ext_vector_type(4))) float f32x4;

__device__ __forceinline__ unsigned short f2bf(float f) {  // RNE fp32->bf16
  unsigned u = __float_as_uint(f);
  u += 0x7FFFu + ((u >> 16) & 1u);
  return (unsigned short)(u >> 16);
}
__device__ __forceinline__ unsigned pack_trunc2(float a, float b) {  // exact for 0/1
  return (__float_as_uint(b) & 0xFFFF0000u) | (__float_as_uint(a) >> 16);
}
__device__ __forceinline__ void async_copy16(const void* gptr, void* lptr) {
  __builtin_amdgcn_global_load_lds((const __attribute__((address_space(1))) unsigned int*)gptr,
                                   (__attribute__((address_space(3))) unsigned int*)lptr,
                                   16, 0, 0);
}

// ---------------- K0: weight transpose to bf16 ----------------
__global__ void k0_transpose_w(const float* __restrict__ W0, const float* __restrict__ W1,
                               unsigned short* __restrict__ W0T, unsigned short* __restrict__ W1T) {
  const float* W = blockIdx.y ? W1 : W0;
  unsigned short* WT = blockIdx.y ? W1T : W0T;
  int n = blockIdx.x;
  int k = threadIdx.x;
  WT[n * CH + k] = f2bf(W[k * CH + n]);
}

// ---------------- K1: rowsum -> node_card; b1h (n-major) + b1hT (e-major) ----------
__global__ __launch_bounds__(256) void k1_prep(const float* __restrict__ B1,
                                               unsigned short* __restrict__ b1h,
                                               unsigned short* __restrict__ b1hT,
                                               float* __restrict__ node_card) {
  __shared__ unsigned short lds_t[64 * 64];
  __shared__ float rs[64][4];
  const int tid = threadIdx.x;
  const int n0 = blockIdx.x * 64;
  const int r = tid >> 2, cb = (tid & 3) * 16;
  float rsum = 0.f;
  for (int e0 = 0; e0 < NE; e0 += 64) {
    const float4* src = (const float4*)(B1 + (size_t)(n0 + r) * NE + e0 + cb);
    unsigned sh[8];
#pragma unroll
    for (int q = 0; q < 4; ++q) {
      float4 v = src[q];
      rsum += v.x + v.y + v.z + v.w;
      sh[q * 2 + 0] = pack_trunc2(v.x, v.y);
      sh[q * 2 + 1] = pack_trunc2(v.z, v.w);
    }
    uint4* dst = (uint4*)(b1h + (size_t)(n0 + r) * NE + e0 + cb);
    dst[0] = make_uint4(sh[0], sh[1], sh[2], sh[3]);
    dst[1] = make_uint4(sh[4], sh[5], sh[6], sh[7]);
    __syncthreads();  // previous tile's readback done
    const unsigned short* sh16 = (const unsigned short*)sh;
#pragma unroll
    for (int j = 0; j < 16; ++j) lds_t[(cb + j) * 64 + r] = sh16[j];
    __syncthreads();
    uint4* tdst = (uint4*)(b1hT + (size_t)(e0 + r) * NN + n0 + cb);
    const uint4* tsrc = (const uint4*)&lds_t[r * 64 + cb];
    tdst[0] = tsrc[0];
    tdst[1] = tsrc[1];
  }
  rs[r][tid & 3] = rsum;
  __syncthreads();
  if (tid < 64) {
    float t = rs[tid][0] + rs[tid][1] + rs[tid][2] + rs[tid][3];
    node_card[n0 + tid] = rsqrtf(t);
  }
}

// ---------------- K2: y0 GEMM + scaled transpose epilogue ----------------
__global__ __launch_bounds__(256) void k2_y0(const float* __restrict__ X0,
                                             const unsigned short* __restrict__ W0T,
                                             const float* __restrict__ node_card,
                                             unsigned short* __restrict__ y0sT) {
  __shared__ unsigned short a_lds[64 * 32];
  __shared__ unsigned short b_lds[256 * 32];
  const int tid = threadIdx.x;
  const int wave = tid >> 6, lane = tid & 63;
  const int quad = lane >> 4, l15 = lane & 15;
  const int m0 = blockIdx.x * 64;
  const int ar = tid >> 3, ac = (tid & 7) * 4;

  f32x4 acc[4][4];
  const f32x4 fz = {0.f, 0.f, 0.f, 0.f};
#pragma unroll
  for (int i = 0; i < 4; ++i)
#pragma unroll
    for (int j = 0; j < 4; ++j) acc[i][j] = fz;

  for (int k0 = 0; k0 < CH; k0 += 32) {
    __syncthreads();
#pragma unroll
    for (int p = 0; p < 2; ++p) {
      float4 v = *(const float4*)(X0 + (size_t)(m0 + ar + p * 32) * CH + k0 + ac);
      uint2 w;
      w.x = ((unsigned)f2bf(v.x)) | ((unsigned)f2bf(v.y) << 16);
      w.y = ((unsigned)f2bf(v.z)) | ((unsigned)f2bf(v.w) << 16);
      *(uint2*)&a_lds[(ar + p * 32) * 32 + ac] = w;
    }
#pragma unroll
    for (int i = 0; i < 4; ++i) {
      int rowbase = wave * 64 + i * 16;
      const unsigned short* g = W0T + (size_t)(rowbase + (lane >> 2)) * CH + k0 + (lane & 3) * 8;
      async_copy16(g, &b_lds[rowbase * 32]);
    }
    __syncthreads();
    bf16x8 af[4];
#pragma unroll
    for (int i = 0; i < 4; ++i)
      af[i] = *(const bf16x8*)&a_lds[(i * 16 + l15) * 32 + quad * 8];
#pragma unroll
    for (int j = 0; j < 4; ++j) {
      bf16x8 bfr = *(const bf16x8*)&b_lds[(wave * 64 + j * 16 + l15) * 32 + quad * 8];
#pragma unroll
      for (int i = 0; i < 4; ++i)
        acc[i][j] = __builtin_amdgcn_mfma_f32_16x16x32_bf16(af[i], bfr, acc[i][j], 0, 0, 0);
    }
  }
#pragma unroll
  for (int i = 0; i < 4; ++i) {
    int row4 = m0 + i * 16 + quad * 4;
    float4 nc = *(const float4*)(node_card + row4);
#pragma unroll
    for (int j = 0; j < 4; ++j) {
      int col = wave * 64 + j * 16 + l15;
      f32x4 v = acc[i][j];
      ushort4 o;
      o.x = f2bf(v[0] * nc.x);
      o.y = f2bf(v[1] * nc.y);
      o.z = f2bf(v[2] * nc.z);
      o.w = f2bf(v[3] * nc.w);
      *(ushort4*)&y0sT[(size_t)col * NN + row4] = o;
    }
  }
}

// ---------------- K2b: y0sT aux rows ----------------
__global__ void k2b_aux(const float* __restrict__ node_card, unsigned short* __restrict__ y0sT) {
  int n = blockIdx.x * 256 + threadIdx.x;
  y0sT[(size_t)256 * NN + n] = f2bf(node_card[n]);
  y0sT[(size_t)257 * NN + n] = 0x3F80;  // 1.0 bf16
#pragma unroll
  for (int r = 258; r < 272; ++r) y0sT[(size_t)r * NN + n] = 0;
}

// ------- MM core: outT[sp][272][Nsz] = Y(272 x K, L2-hot) @ Bm(Nsz x K, streaming) -----
// Both operands [row][k] bf16, k-contiguous. async_copy16 direct for both; source-side
// XOR chunk swizzle (chunk ^= (row>>1)&3) makes frag ds_read_b128 2-way (free).
template <int NSZ, int SPLIT>
__device__ __forceinline__ void mm_core(const unsigned short* __restrict__ Y,
                                        const unsigned short* __restrict__ Bm,
                                        float* __restrict__ outp) {
  __shared__ unsigned short a_lds[272 * 32];
  __shared__ unsigned short b_lds[64 * 32];
  const int tid = threadIdx.x;
  const int wave = tid >> 6, lane = tid & 63;
  const int quad = lane >> 4, l15 = lane & 15;
  const int bid = blockIdx.x;
  const int sp = bid & (SPLIT - 1);  // splitK slice -> XCD (round-robin dispatch)
  const int n0 = (bid / SPLIT) * 64;
  const int K = (NSZ == NE) ? NN : NE;
  const int KS = K / SPLIT;
  const int kbase = sp * KS;
  const int lr = lane >> 2;                       // local row in a 16-row group
  const int csw = (lane & 3) ^ ((lane >> 3) & 3); // staged source chunk for this lane
  const int rquad = quad ^ ((l15 >> 1) & 3);      // frag-read chunk

  f32x4 acc[4][4];
  f32x4 acc5[4];
  const f32x4 fz = {0.f, 0.f, 0.f, 0.f};
#pragma unroll
  for (int i = 0; i < 4; ++i) {
    acc5[i] = fz;
#pragma unroll
    for (int j = 0; j < 4; ++j) acc[i][j] = fz;
  }

  for (int kk = 0; kk < KS; kk += 32) {
    const int k0 = kbase + kk;
    __syncthreads();
    // stage A (Y): 272 rows = 17 groups of 16
#pragma unroll
    for (int i = 0; i < 4; ++i) {
      int row0 = (wave * 4 + i) * 16;
      const unsigned short* g = Y + (size_t)(row0 + lr) * K + k0 + csw * 8;
      async_copy16(g, &a_lds[row0 * 32]);
    }
    if (wave == 3) {
      const unsigned short* g = Y + (size_t)(256 + lr) * K + k0 + csw * 8;
      async_copy16(g, &a_lds[256 * 32]);
    }
    // stage B (streaming b1h/b1hT rows): 64 rows = 4 groups of 16
    {
      const unsigned short* g = Bm + (size_t)(n0 + wave * 16 + lr) * K + k0 + csw * 8;
      async_copy16(g, &b_lds[(wave * 16) * 32]);
    }
    __syncthreads();
    bf16x8 af[5];
#pragma unroll
    for (int i = 0; i < 4; ++i)
      af[i] = *(const bf16x8*)&a_lds[((wave * 4 + i) * 16 + l15) * 32 + rquad * 8];
    if (wave == 3) af[4] = *(const bf16x8*)&a_lds[(256 + l15) * 32 + rquad * 8];
#pragma unroll
    for (int j = 0; j < 4; ++j) {
      bf16x8 bfr = *(const bf16x8*)&b_lds[(j * 16 + l15) * 32 + rquad * 8];
#pragma unroll
      for (int i = 0; i < 4; ++i)
        acc[i][j] = __builtin_amdgcn_mfma_f32_16x16x32_bf16(af[i], bfr, acc[i][j], 0, 0, 0);
      if (wave == 3)
        acc5[j] = __builtin_amdgcn_mfma_f32_16x16x32_bf16(af[4], bfr, acc5[j], 0, 0, 0);
    }
  }
  float* op = outp + (size_t)sp * 272 * NSZ;
#pragma unroll
  for (int i = 0; i < 4; ++i) {
    int cbase = (wave * 4 + i) * 16 + quad * 4;
#pragma unroll
    for (int j = 0; j < 4; ++j) {
      int n = n0 + j * 16 + l15;
#pragma unroll
      for (int r = 0; r < 4; ++r) op[(size_t)(cbase + r) * NSZ + n] = acc[i][j][r];
    }
  }
  if (wave == 3) {
    int cbase = 256 + quad * 4;
#pragma unroll
    for (int j = 0; j < 4; ++j) {
      int n = n0 + j * 16 + l15;
#pragma unroll
      for (int r = 0; r < 4; ++r) op[(size_t)(cbase + r) * NSZ + n] = acc5[j][r];
    }
  }
}

__global__ __launch_bounds__(256, 4) void mm1t_kernel(const unsigned short* __restrict__ y0sT,
                                                      const unsigned short* __restrict__ b1hT,
                                                      float* __restrict__ mm1pT) {
  mm_core<NE, MM1_SPLIT>(y0sT, b1hT, mm1pT);
}
__global__ __launch_bounds__(256, 4) void mm2t_kernel(const unsigned short* __restrict__ y1sT,
                                                      const unsigned short* __restrict__ b1h,
                                                      float* __restrict__ mm2pT) {
  mm_core<NN, MM2_SPLIT>(y1sT, b1h, mm2pT);
}

// ---------------- K3: reduce partials + finalize edges (transpose epilogue) --------
__global__ __launch_bounds__(256) void k3_edge_final(const float* __restrict__ mm1pT,
                                                     const float* __restrict__ b01,
                                                     float* __restrict__ out1,
                                                     unsigned short* __restrict__ x1bf,
                                                     float* __restrict__ edge_card) {
  __shared__ float tile[32 * 260];
  __shared__ float d1s[32], css[32];
  const int tid = threadIdx.x;
  const int e0 = blockIdx.x * 32;
  float p[32];
#pragma unroll
  for (int u = 0; u < 32; ++u) p[u] = 0.f;
  for (int sp = 0; sp < MM1_SPLIT; ++sp) {
    const float4* rp = (const float4*)(mm1pT + ((size_t)sp * 272 + tid) * NE + e0);
#pragma unroll
    for (int u = 0; u < 8; ++u) {
      float4 v = rp[u];
      p[u * 4 + 0] += v.x; p[u * 4 + 1] += v.y; p[u * 4 + 2] += v.z; p[u * 4 + 3] += v.w;
    }
  }
  if (tid < 64) {
    int row = 256 + (tid >> 5), e = e0 + (tid & 31);
    float s = 0.f;
    for (int sp = 0; sp < MM1_SPLIT; ++sp) s += mm1pT[((size_t)sp * 272 + row) * NE + e];
    if (tid < 32) d1s[tid] = s; else css[tid & 31] = s;
  }
  __syncthreads();
  float bc = b01[tid];
#pragma unroll
  for (int u = 0; u < 32; ++u) tile[u * 260 + tid] = p[u] / d1s[u] + bc;
  if (tid < 32) {
    float cs = css[tid];
    edge_card[e0 + tid] = 1.0f / (cs * sqrtf(cs));
  }
  __syncthreads();
  const int e = tid >> 3, cb = (tid & 7) * 32;
  const float* trow = &tile[e * 260 + cb];
  float* orow = out1 + (size_t)(e0 + e) * CH + cb;
  unsigned short* xrow = x1bf + (size_t)(e0 + e) * CH + cb;
#pragma unroll
  for (int v = 0; v < 32; v += 4) {
    float4 x;
    x.x = trow[v]; x.y = trow[v + 1]; x.z = trow[v + 2]; x.w = trow[v + 3];
    float4 rl;
    rl.x = fmaxf(x.x, 0.f); rl.y = fmaxf(x.y, 0.f); rl.z = fmaxf(x.z, 0.f); rl.w = fmaxf(x.w, 0.f);
    *(float4*)&orow[v] = rl;
    ushort4 h;
    h.x = f2bf(x.x); h.y = f2bf(x.y); h.z = f2bf(x.z); h.w = f2bf(x.w);
    *(ushort4*)&xrow[v] = h;
  }
}

// ---------------- K5: y1 GEMM + scaled transpose epilogue ----------------
__global__ __launch_bounds__(256) void k5_y1(const unsigned short* __restrict__ x1bf,
                                             const unsigned short* __restrict__ W1T,
                                             const float* __restrict__ edge_card,
                                             unsigned short* __restrict__ y1sT) {
  __shared__ unsigned short a_lds[64 * 32];
  __shared__ unsigned short b_lds[256 * 32];
  const int tid = threadIdx.x;
  const int wave = tid >> 6, lane = tid & 63;
  const int quad = lane >> 4, l15 = lane & 15;
  const int m0 = blockIdx.x * 64;  // e-range

  f32x4 acc[4][4];
  const f32x4 fz = {0.f, 0.f, 0.f, 0.f};
#pragma unroll
  for (int i = 0; i < 4; ++i)
#pragma unroll
    for (int j = 0; j < 4; ++j) acc[i][j] = fz;

  for (int k0 = 0; k0 < CH; k0 += 32) {
    __syncthreads();
    {
      const unsigned short* g = x1bf + (size_t)(m0 + wave * 16 + (lane >> 2)) * CH + k0 + (lane & 3) * 8;
      async_copy16(g, &a_lds[(wave * 16) * 32]);
    }
#pragma unroll
    for (int i = 0; i < 4; ++i) {
      int rowbase = wave * 64 + i * 16;
      const unsigned short* g = W1T + (size_t)(rowbase + (lane >> 2)) * CH + k0 + (lane & 3) * 8;
      async_copy16(g, &b_lds[rowbase * 32]);
    }
    __syncthreads();
    bf16x8 af[4];
#pragma unroll
    for (int i = 0; i < 4; ++i)
      af[i] = *(const bf16x8*)&a_lds[(i * 16 + l15) * 32 + quad * 8];
#pragma unroll
    for (int j = 0; j < 4; ++j) {
      bf16x8 bfr = *(const bf16x8*)&b_lds[(wave * 64 + j * 16 + l15) * 32 + quad * 8];
#pragma unroll
      for (int i = 0; i < 4; ++i)
        acc[i][j] = __builtin_amdgcn_mfma_f32_16x16x32_bf16(af[i], bfr, acc[i][j], 0, 0, 0);
    }
  }
#pragma unroll
  for (int i = 0; i < 4; ++i) {
    int row4 = m0 + i * 16 + quad * 4;
    float4 ec = *(const float4*)(edge_card + row4);
#pragma unroll
    for (int j = 0; j < 4; ++j) {
      int col = wave * 64 + j * 16 + l15;
      f32x4 v = acc[i][j];
      ushort4 o;
      o.x = f2bf(v[0] * ec.x);
      o.y = f2bf(v[1] * ec.y);
      o.z = f2bf(v[2] * ec.z);
      o.w = f2bf(v[3] * ec.w);
      *(ushort4*)&y1sT[(size_t)col * NE + row4] = o;
    }
  }
}

// ---------------- K5b: y1sT aux rows ----------------
__global__ void k5b_aux(const float* __restrict__ edge_card, unsigned short* __restrict__ y1sT) {
  int e = blockIdx.x * 256 + threadIdx.x;
  y1sT[(size_t)256 * NE + e] = f2bf(edge_card[e]);
#pragma unroll
  for (int r = 257; r < 272; ++r) y1sT[(size_t)r * NE + e] = 0;
}

// ---------------- K6: reduce partials + finalize nodes (transpose epilogue) --------
__global__ __launch_bounds__(256) void k6_node_final(const float* __restrict__ mm2pT,
                                                     const float* __restrict__ b10,
                                                     float* __restrict__ out0) {
  __shared__ float tile[32 * 260];
  __shared__ float d0s[32];
  const int tid = threadIdx.x;
  const int n0 = blockIdx.x * 32;
  float p[32];
#pragma unroll
  for (int u = 0; u < 32; ++u) p[u] = 0.f;
  for (int sp = 0; sp < MM2_SPLIT; ++sp) {
    const float4* rp = (const float4*)(mm2pT + ((size_t)sp * 272 + tid) * NN + n0);
#pragma unroll
    for (int u = 0; u < 8; ++u) {
      float4 v = rp[u];
      p[u * 4 + 0] += v.x; p[u * 4 + 1] += v.y; p[u * 4 + 2] += v.z; p[u * 4 + 3] += v.w;
    }
  }
  if (tid < 32) {
    float s = 0.f;
    for (int sp = 0; sp < MM2_SPLIT; ++sp) s += mm2pT[((size_t)sp * 272 + 256) * NN + n0 + tid];
    d0s[tid] = s;
  }
  __syncthreads();
  float bc = b10[tid];
#pragma unroll
  for (int u = 0; u < 32; ++u) tile[u * 260 + tid] = p[u] / d0s[u] + bc;
  __syncthreads();
  const int n = tid >> 3, cb = (tid & 7) * 32;
  const float* trow = &tile[n * 260 + cb];
  float* orow = out0 + (size_t)(n0 + n) * CH + cb;
#pragma unroll
  for (int v = 0; v < 32; v += 4) {
    float4 x;
    x.x = trow[v]; x.y = trow[v + 1]; x.z = trow[v + 2]; x.w = trow[v + 3];
    float4 rl;
    rl.x = fmaxf(x.x, 0.f); rl.y = fmaxf(x.y, 0.f); rl.z = fmaxf(x.z, 0.f); rl.w = fmaxf(x.w, 0.f);
    *(float4*)&orow[v] = rl;
  }
}

extern "C" void kernel_launch(void* const* d_in, const int* in_sizes, int n_in,
                              void* d_out, int out_size, void* d_ws, size_t ws_size,
                              hipStream_t stream) {
  const float* x0 = (const float*)d_in[0];
  const float* B1 = (const float*)d_in[1];
  const float* W0 = (const float*)d_in[2];
  const float* W1 = (const float*)d_in[3];
  const float* b01 = (const float*)d_in[4];
  const float* b10 = (const float*)d_in[5];
  float* out0 = (float*)d_out;
  float* out1 = out0 + (size_t)NN * CH;

  char* ws = (char*)d_ws;
  size_t off = 0;
  auto take = [&](size_t bytes) {
    void* p = ws + off;
    off += (bytes + 255) & ~(size_t)255;
    return p;
  };
  unsigned short* b1h = (unsigned short*)take((size_t)NN * NE * 2);    // 268 MB [n][e]
  unsigned short* b1hT = (unsigned short*)take((size_t)NN * NE * 2);   // 268 MB [e][n]
  unsigned short* y0sT = (unsigned short*)take((size_t)272 * NN * 2);  // 8.9 MB
  unsigned short* y1sT = (unsigned short*)take((size_t)272 * NE * 2);  // 4.5 MB
  unsigned short* x1bf = (unsigned short*)take((size_t)NE * CH * 2);   // 4.2 MB
  float* mm1pT = (float*)take((size_t)MM1_SPLIT * 272 * NE * 4);       // 71.3 MB
  float* mm2pT = mm1pT;  // alias: mm1pT dead after K3; MM2_SPLIT*272*NN*4 same size
  float* node_card = (float*)take((size_t)NN * 4);
  float* edge_card = (float*)take((size_t)NE * 4);
  unsigned short* W0T = (unsigned short*)take((size_t)CH * CH * 2);
  unsigned short* W1T = (unsigned short*)take((size_t)CH * CH * 2);
  (void)ws_size; (void)in_sizes; (void)n_in; (void)out_size;

  k0_transpose_w<<<dim3(256, 2), 256, 0, stream>>>(W0, W1, W0T, W1T);
  k1_prep<<<NN / 64, 256, 0, stream>>>(B1, b1h, b1hT, node_card);
  k2_y0<<<NN / 64, 256, 0, stream>>>(x0, W0T, node_card, y0sT);
  k2b_aux<<<NN / 256, 256, 0, stream>>>(node_card, y0sT);
  mm1t_kernel<<<(NE / 64) * MM1_SPLIT, 256, 0, stream>>>(y0sT, b1hT, mm1pT);
  k3_edge_final<<<NE / 32, 256, 0, stream>>>(mm1pT, b01, out1, x1bf, edge_card);
  k5_y1<<<NE / 64, 256, 0, stream>>>(x1bf, W1T, edge_card, y1sT);
  k5b_aux<<<NE / 256, 256, 0, stream>>>(edge_card, y1sT);
  mm2t_kernel<<<(NN / 64) * MM2_SPLIT, 256, 0, stream>>>(y1sT, b1h, mm2pT);
  k6_node_final<<<NN / 32, 256, 0, stream>>>(mm2pT, b10, out0);
}